// Round 5
// baseline (276.568 us; speedup 1.0000x reference)
//
#include <hip/hip_runtime.h>
#include <cfloat>

#define NB 4
#define NN 4096
#define NC 256

typedef _Float16 f16;
typedef _Float16 f16x8 __attribute__((ext_vector_type(8)));
typedef float f32x4 __attribute__((ext_vector_type(4)));

__device__ __forceinline__ void gl_lds16(const void* g, void* l) {
    __builtin_amdgcn_global_load_lds(
        (const __attribute__((address_space(1))) unsigned int*)g,
        (__attribute__((address_space(3))) unsigned int*)l, 16, 0, 0);
}

// ---------------- prep: fp32 -> f16 hi/lo split + diag ----------------
__global__ __launch_bounds__(256) void prep_kernel(const float* __restrict__ x,
                                                   f16* __restrict__ xh,
                                                   f16* __restrict__ xl,
                                                   float* __restrict__ diag) {
    const int lane = threadIdx.x & 63;
    const int wave = threadIdx.x >> 6;
    const int row  = (blockIdx.x << 2) + wave;            // 0..16383
    const float4 v = ((const float4*)(x + (size_t)row * NC))[lane];
    union { f16 h[4]; uint2 u; } H, L;
    float vv[4] = {v.x, v.y, v.z, v.w};
    float s = 0.f;
    #pragma unroll
    for (int k = 0; k < 4; ++k) {
        H.h[k] = (f16)vv[k];
        L.h[k] = (f16)(vv[k] - (float)H.h[k]);
        s = fmaf(vv[k], vv[k], s);
    }
    *(uint2*)(xh + (size_t)row * NC + lane * 4) = H.u;
    *(uint2*)(xl + (size_t)row * NC + lane * 4) = L.u;
    #pragma unroll
    for (int off = 32; off; off >>= 1) s += __shfl_xor(s, off, 64);
    if (lane == 0) diag[row] = s;
}

// ---------------- main MFMA kernel ----------------
// Barrier-free K-loop (r4) + register-level software pipeline (r5):
// each wave owns a private 64-col B stripe; the 48-MFMA chunk is split into
// 4 quarters by rt. A-frags rotate in place (af[rt] dead after quarter rt);
// B-frags ping-pong (bA/bB). All frag reads for chunk g+1 are placed between
// quarters of chunk g, so LDS-read latency/throughput hides under the MFMA
// pipe WITHIN a wave instead of relying on cross-wave anti-phase.
#define TI 64
#define TJ 512
#define KCB 32
#define NCHUNK (NC / KCB)    // 8 k-chunks per j-tile
#define NJT (NN / TJ)        // 8 j-tiles
#define NGC (NJT * NCHUNK)   // 64 chunks total

#define TRIPLE(RT, CT, BH, BL) \
    acc[RT][CT] = __builtin_amdgcn_mfma_f32_16x16x32_f16(afh[RT], BH[CT], acc[RT][CT], 0, 0, 0); \
    acc[RT][CT] = __builtin_amdgcn_mfma_f32_16x16x32_f16(afh[RT], BL[CT], acc[RT][CT], 0, 0, 0); \
    acc[RT][CT] = __builtin_amdgcn_mfma_f32_16x16x32_f16(afl[RT], BH[CT], acc[RT][CT], 0, 0, 0);

#define QUARTER(RT, BH, BL) \
    __builtin_amdgcn_s_setprio(1); \
    TRIPLE(RT, 0, BH, BL) TRIPLE(RT, 1, BH, BL) TRIPLE(RT, 2, BH, BL) TRIPLE(RT, 3, BH, BL) \
    __builtin_amdgcn_s_setprio(0);

// A-frag read for k-chunk KN into slot RT (Ah layout: slot g holds granule g^(row&7))
#define RDA(RT, KN) \
    afh[RT] = *(const f16x8*)&Ah[((RT) * 16 + l15) * NC + ((((KN) * 4 + quad) ^ sw) * 8)]; \
    afl[RT] = *(const f16x8*)&Al[((RT) * 16 + l15) * NC + ((((KN) * 4 + quad) ^ sw) * 8)];

// one k-chunk, fully static (KC literal). CUR frags were read one chunk ago.
#define CHUNK(KC, BHC, BLC, BHN, BLN) do { \
    /* stripe-clobber guard: only the 8 stripe reads must drain; the 2     */ \
    /* trailing A-reads (newest outstanding) may still fly.                */ \
    asm volatile("s_waitcnt lgkmcnt(2)" ::: "memory"); \
    __builtin_amdgcn_sched_barrier(0); \
    if (!((KC) == 7 && jt == NJT - 1)) { \
        const int jn = ((KC) == 7) ? jt + 1 : jt; \
        _Pragma("unroll") \
        for (int t = 0; t < 4; ++t) { \
            const int col = jn * TJ + w * 64 + t * 16 + bcol; \
            const size_t goff = (size_t)col * NC + ((KC + 1) & 7) * KCB + bslot * 8; \
            gl_lds16(xhb + goff, swh + t * 512); \
            gl_lds16(xlb + goff, swl + t * 512); \
        } \
    } \
    __builtin_amdgcn_sched_barrier(0); \
    QUARTER(0, BHC, BLC) \
    RDA(0, ((KC) + 1) & 7) \
    __builtin_amdgcn_sched_barrier(0); \
    QUARTER(1, BHC, BLC) \
    RDA(1, ((KC) + 1) & 7) \
    __builtin_amdgcn_sched_barrier(0); \
    QUARTER(2, BHC, BLC) \
    asm volatile("s_waitcnt vmcnt(0)" ::: "memory"); \
    __builtin_amdgcn_sched_barrier(0); \
    _Pragma("unroll") \
    for (int ct = 0; ct < 4; ++ct) { \
        const int c = ct * 16 + l15; \
        BHN[ct] = *(const f16x8*)&swh[c * KCB + gB]; \
        BLN[ct] = *(const f16x8*)&swl[c * KCB + gB]; \
    } \
    RDA(2, ((KC) + 1) & 7) \
    __builtin_amdgcn_sched_barrier(0); \
    QUARTER(3, BHC, BLC) \
    RDA(3, ((KC) + 1) & 7) \
} while (0)

__global__ __launch_bounds__(512, 2) void fcm_mfma(const f16* __restrict__ xh,
                                                   const f16* __restrict__ xl,
                                                   const float* __restrict__ diag,
                                                   float* __restrict__ out) {
    __shared__ f16 Ah[TI * NC];          // 32 KB  persistent A hi (swizzled)
    __shared__ f16 Al[TI * NC];          // 32 KB  persistent A lo
    __shared__ f16 Sh[8 * 2048];         // 32 KB  wave-private B hi stripes
    __shared__ f16 Sl[8 * 2048];         // 32 KB  wave-private B lo stripes
    __shared__ float Scr[TI * 8 * 3];    // 6 KB   cross-wave merge

    const int tid   = threadIdx.x;
    const int bx    = blockIdx.x;
    const int batch = (bx & 7) >> 1;                  // batch -> XCD pair
    const int band  = ((bx >> 3) << 1) | (bx & 1);    // 0..63
    const int i0    = band * TI;

    const f16* __restrict__ xhb = xh + (size_t)batch * NN * NC;
    const f16* __restrict__ xlb = xl + (size_t)batch * NN * NC;
    const float* __restrict__ db = diag + (size_t)batch * NN;

    const int w    = tid >> 6;
    const int lane = tid & 63;
    const int quad = lane >> 4;
    const int l15  = lane & 15;
    const int sw   = l15 & 7;     // A fragment swizzle key

    // wave-private stripe bases
    f16* const swh = Sh + w * 2048;
    f16* const swl = Sl + w * 2048;

    // ---- A stage (once): LDS[row][granule ^ (row&7)] = x[i0+row][granule] ----
    {
        const int rsub = lane >> 5;        // 0/1
        const int s    = lane & 31;
        #pragma unroll
        for (int it = 0; it < 4; ++it) {
            const int t  = w * 4 + it;     // 0..31, 2 rows each
            const int rg = t * 2 + rsub;
            const int g  = s ^ (rg & 7);
            const size_t goff = (size_t)(i0 + rg) * NC + g * 8;
            gl_lds16(xhb + goff, Ah + t * 512);
            gl_lds16(xlb + goff, Al + t * 512);
        }
    }

    // B staging lane constants (16 cols x 4 granules per 1KB wave-instr)
    const int bcol  = lane >> 2;                       // col within 16-col group
    const int bslot = (lane & 3) ^ ((lane >> 3) & 3);  // source granule for this slot
    const int gB    = (quad ^ ((l15 >> 1) & 3)) * 8;   // B frag read granule (const)

    // ---- prologue: stage stripe for chunk 0 (jt=0,kc=0) ----
    #pragma unroll
    for (int t = 0; t < 4; ++t) {
        const int col = w * 64 + t * 16 + bcol;
        const size_t goff = (size_t)col * NC + bslot * 8;
        gl_lds16(xhb + goff, swh + t * 512);
        gl_lds16(xlb + goff, swl + t * 512);
    }
    __syncthreads();      // drains A + stripe0; the ONLY barrier before epilogue

    // frag registers: af rotates in place, bf ping-pongs
    f16x8 afh[4], afl[4];
    f16x8 bAh[4], bAl[4], bBh[4], bBl[4];

    // preload frags for chunk 0: B FIRST (so the newest outstanding lgkm ops
    // at CHUNK(0)'s lgkmcnt(2) are A-reads, never stripe reads)
    #pragma unroll
    for (int ct = 0; ct < 4; ++ct) {
        const int c = ct * 16 + l15;
        bAh[ct] = *(const f16x8*)&swh[c * KCB + gB];
        bAl[ct] = *(const f16x8*)&swl[c * KCB + gB];
    }
    RDA(0, 0) RDA(1, 0) RDA(2, 0) RDA(3, 0)

    // running top-2 (+argmin) for the lane's 16 row-slots (rt*4 + p)
    float m1[16], m2[16]; int i1[16];
    #pragma unroll
    for (int r = 0; r < 16; ++r) { m1[r] = FLT_MAX; m2[r] = FLT_MAX; i1[r] = 0x7fffffff; }

    for (int jt = 0; jt < NJT; ++jt) {
        f32x4 acc[4][4];
        #pragma unroll
        for (int rt = 0; rt < 4; ++rt)
            #pragma unroll
            for (int ct = 0; ct < 4; ++ct)
                acc[rt][ct] = (f32x4){0.f, 0.f, 0.f, 0.f};

        CHUNK(0, bAh, bAl, bBh, bBl);
        CHUNK(1, bBh, bBl, bAh, bAl);
        CHUNK(2, bAh, bAl, bBh, bBl);
        CHUNK(3, bBh, bBl, bAh, bAl);
        CHUNK(4, bAh, bAl, bBh, bBl);
        CHUNK(5, bBh, bBl, bAh, bAl);
        CHUNK(6, bAh, bAl, bBh, bBl);
        CHUNK(7, bBh, bBl, bAh, bAl);

        // fold j-tile into running top-2; key = diag_j - 2*dot (monotone in dist)
        #pragma unroll
        for (int ct = 0; ct < 4; ++ct) {
            const int col = jt * TJ + w * 64 + ct * 16 + l15;
            const float dj = db[col];                  // L2-hot, once per j-tile
            #pragma unroll
            for (int rt = 0; rt < 4; ++rt) {
                #pragma unroll
                for (int p = 0; p < 4; ++p) {
                    const int rglob = i0 + rt * 16 + quad * 4 + p;
                    float v = fmaf(-2.0f, acc[rt][ct][p], dj);
                    v = (col == rglob) ? FLT_MAX : v;       // mask self
                    const int slot = rt * 4 + p;
                    const bool lt = v < m1[slot];           // strict: keep earliest j
                    m2[slot] = fminf(m2[slot], fmaxf(m1[slot], v));
                    m1[slot] = fminf(m1[slot], v);
                    i1[slot] = lt ? col : i1[slot];
                }
            }
        }
    }

    // butterfly merge across the 16 col-lanes (l15) holding the same rows
    #pragma unroll
    for (int s = 0; s < 16; ++s) {
        float a1 = m1[s], a2 = m2[s]; int ai = i1[s];
        #pragma unroll
        for (int msk = 1; msk < 16; msk <<= 1) {
            const float o1 = __shfl_xor(a1, msk, 64);
            const float o2 = __shfl_xor(a2, msk, 64);
            const int   oi = __shfl_xor(ai, msk, 64);
            const bool take = (o1 < a1) || (o1 == a1 && oi < ai);
            const float keep = take ? a1 : o1;
            a2 = fminf(fminf(a2, o2), keep);
            a1 = take ? o1 : a1;
            ai = take ? oi : ai;
        }
        m1[s] = a1; m2[s] = a2; i1[s] = ai;
    }
    if (l15 == 0) {
        #pragma unroll
        for (int s = 0; s < 16; ++s) {
            const int rloc = (s >> 2) * 16 + quad * 4 + (s & 3);
            float* p = &Scr[(rloc * 8 + w) * 3];
            p[0] = m1[s]; p[1] = __int_as_float(i1[s]); p[2] = m2[s];
        }
    }
    __syncthreads();
    if (tid < TI) {
        float M1 = FLT_MAX, M2 = FLT_MAX; int I1 = 0x7fffffff;
        #pragma unroll
        for (int t = 0; t < 8; ++t) {
            const float* p = &Scr[(tid * 8 + t) * 3];
            const float o1 = p[0]; const int oi = __float_as_int(p[1]); const float o2 = p[2];
            const bool take = (o1 < M1) || (o1 == M1 && oi < I1);
            const float keep = take ? M1 : o1;
            M2 = fminf(fminf(M2, o2), keep);
            M1 = take ? o1 : M1;
            I1 = take ? oi : I1;
        }
        const int   gi = i0 + tid;
        const float di = db[gi];
        const float d1 = sqrtf(fmaxf(di + M1, 0.0f) + 1e-9f);
        const float d2 = sqrtf(fmaxf(di + M2, 0.0f) + 1e-9f);
        const float e  = expf(d1);
        const float pred = (d1 / d2 < 0.6f) ? 2.0f / (1.0f + e)
                                            : 2.0f / (1.0f + 2.0f * e);
        out[(size_t)batch * NN + gi] = pred;
        out[(size_t)NB * NN + (size_t)batch * NN + gi] = (float)I1;
    }
}

// ---------------- fp32 fallback (round-1, passed) if ws too small ----------------
__global__ __launch_bounds__(256) void diag_kernel(const float* __restrict__ x,
                                                   float* __restrict__ diag) {
    const int lane = threadIdx.x & 63;
    const int wave = threadIdx.x >> 6;
    const int row  = (blockIdx.x << 2) + wave;
    const float4 v = ((const float4*)(x + (size_t)row * NC))[lane];
    float s = v.x * v.x + v.y * v.y + v.z * v.z + v.w * v.w;
    #pragma unroll
    for (int off = 32; off; off >>= 1) s += __shfl_xor(s, off, 64);
    if (lane == 0) diag[row] = s;
}

#define FTI 64
#define FTJ 256
#define FKC 16

__global__ __launch_bounds__(256) void fcm_fallback(const float* __restrict__ x,
                                                    const float* __restrict__ diag,
                                                    float* __restrict__ out) {
    __shared__ float As[FKC * FTI];
    __shared__ float Bs[FKC * FTJ];
    __shared__ float Dsf[FTJ];
    __shared__ float Scrf[FTI * 32 * 3];

    const int tid = threadIdx.x;
    const int bx  = blockIdx.x;
    const int batch = (bx & 7) >> 1;
    const int tile  = ((bx >> 3) << 1) | (bx & 1);
    const int i0    = tile * FTI;
    const float* __restrict__ xb = x + (size_t)batch * NN * NC;
    const float* __restrict__ db = diag + (size_t)batch * NN;
    const int tx = tid & 31;
    const int ty = tid >> 5;
    const int sr  = tid & 63;
    const int sk0 = (tid >> 6) << 2;

    float m1[8], m2[8]; int i1[8];
    #pragma unroll
    for (int r = 0; r < 8; ++r) { m1[r] = FLT_MAX; m2[r] = FLT_MAX; i1[r] = 0; }

    for (int jt = 0; jt < NN / FTJ; ++jt) {
        const int j0 = jt * FTJ;
        __syncthreads();
        Dsf[tid] = db[j0 + tid];
        float acc[8][8];
        #pragma unroll
        for (int r = 0; r < 8; ++r)
            #pragma unroll
            for (int c = 0; c < 8; ++c) acc[r][c] = 0.0f;
        float4 pa  = *(const float4*)(xb + (size_t)(i0 + sr) * NC + sk0);
        const float* bsrc = xb + (size_t)(j0 + tid) * NC;
        float4 pb0 = *(const float4*)(bsrc + 0);
        float4 pb1 = *(const float4*)(bsrc + 4);
        float4 pb2 = *(const float4*)(bsrc + 8);
        float4 pb3 = *(const float4*)(bsrc + 12);
        for (int kc = 0; kc < NC / FKC; ++kc) {
            __syncthreads();
            As[(sk0 + 0) * FTI + sr] = pa.x;
            As[(sk0 + 1) * FTI + sr] = pa.y;
            As[(sk0 + 2) * FTI + sr] = pa.z;
            As[(sk0 + 3) * FTI + sr] = pa.w;
            Bs[ 0 * FTJ + tid] = pb0.x; Bs[ 1 * FTJ + tid] = pb0.y;
            Bs[ 2 * FTJ + tid] = pb0.z; Bs[ 3 * FTJ + tid] = pb0.w;
            Bs[ 4 * FTJ + tid] = pb1.x; Bs[ 5 * FTJ + tid] = pb1.y;
            Bs[ 6 * FTJ + tid] = pb1.z; Bs[ 7 * FTJ + tid] = pb1.w;
            Bs[ 8 * FTJ + tid] = pb2.x; Bs[ 9 * FTJ + tid] = pb2.y;
            Bs[10 * FTJ + tid] = pb2.z; Bs[11 * FTJ + tid] = pb2.w;
            Bs[12 * FTJ + tid] = pb3.x; Bs[13 * FTJ + tid] = pb3.y;
            Bs[14 * FTJ + tid] = pb3.z; Bs[15 * FTJ + tid] = pb3.w;
            if (kc + 1 < NC / FKC) {
                const int kb = (kc + 1) * FKC;
                pa  = *(const float4*)(xb + (size_t)(i0 + sr) * NC + kb + sk0);
                pb0 = *(const float4*)(bsrc + kb + 0);
                pb1 = *(const float4*)(bsrc + kb + 4);
                pb2 = *(const float4*)(bsrc + kb + 8);
                pb3 = *(const float4*)(bsrc + kb + 12);
            }
            __syncthreads();
            #pragma unroll
            for (int k = 0; k < FKC; ++k) {
                float av[8], bv[8];
                *(float4*)&av[0] = *(const float4*)&As[k * FTI + ty * 8];
                *(float4*)&av[4] = *(const float4*)&As[k * FTI + ty * 8 + 4];
                *(float4*)&bv[0] = *(const float4*)&Bs[k * FTJ + tx * 8];
                *(float4*)&bv[4] = *(const float4*)&Bs[k * FTJ + tx * 8 + 4];
                #pragma unroll
                for (int r = 0; r < 8; ++r)
                    #pragma unroll
                    for (int c = 0; c < 8; ++c)
                        acc[r][c] = fmaf(av[r], bv[c], acc[r][c]);
            }
        }
        #pragma unroll
        for (int c = 0; c < 8; ++c) {
            const int j = j0 + tx * 8 + c;
            const float dj = Dsf[tx * 8 + c];
            #pragma unroll
            for (int r = 0; r < 8; ++r) {
                const int ig = i0 + ty * 8 + r;
                float v = fmaf(-2.0f, acc[r][c], dj);
                v = (j == ig) ? FLT_MAX : v;
                const bool lt = v < m1[r];
                m2[r] = fminf(m2[r], fmaxf(m1[r], v));
                m1[r] = fminf(m1[r], v);
                i1[r] = lt ? j : i1[r];
            }
        }
    }
    __syncthreads();
    #pragma unroll
    for (int r = 0; r < 8; ++r) {
        float* s = &Scrf[((ty * 8 + r) * 32 + tx) * 3];
        s[0] = m1[r]; s[1] = __int_as_float(i1[r]); s[2] = m2[r];
    }
    __syncthreads();
    if (tid < FTI) {
        float M1 = FLT_MAX, M2 = FLT_MAX; int I1 = 0;
        for (int t = 0; t < 32; ++t) {
            const float* s = &Scrf[(tid * 32 + t) * 3];
            const float v1 = s[0]; const int ii = __float_as_int(s[1]);
            const float v2 = s[2];
            if (v1 < M1 || (v1 == M1 && ii < I1)) {
                M2 = fminf(M2, M1); M1 = v1; I1 = ii;
            } else {
                M2 = fminf(M2, v1);
            }
            M2 = fminf(M2, v2);
        }
        const int   gi = i0 + tid;
        const float di = db[gi];
        const float d1 = sqrtf(fmaxf(di + M1, 0.0f) + 1e-9f);
        const float d2 = sqrtf(fmaxf(di + M2, 0.0f) + 1e-9f);
        const float e  = expf(d1);
        const float pred = (d1 / d2 < 0.6f) ? 2.0f / (1.0f + e)
                                            : 2.0f / (1.0f + 2.0f * e);
        out[(size_t)batch * NN + gi] = pred;
        out[(size_t)NB * NN + (size_t)batch * NN + gi] = (float)I1;
    }
}

extern "C" void kernel_launch(void* const* d_in, const int* in_sizes, int n_in,
                              void* d_out, int out_size, void* d_ws, size_t ws_size,
                              hipStream_t stream) {
    const float* x = (const float*)d_in[0];
    float* out     = (float*)d_out;
    const size_t n_elem = (size_t)NB * NN * NC;
    const size_t need   = n_elem * 2 * 2 + (size_t)NB * NN * 4;   // hi+lo f16 + diag
    if (ws_size >= need) {
        f16*   xh   = (f16*)d_ws;
        f16*   xl   = xh + n_elem;
        float* diag = (float*)(xl + n_elem);
        prep_kernel<<<dim3(NB * NN / 4), dim3(256), 0, stream>>>(x, xh, xl, diag);
        fcm_mfma<<<dim3(256), dim3(512), 0, stream>>>(xh, xl, diag, out);
    } else {
        float* diag = (float*)d_ws;
        diag_kernel<<<dim3(NB * NN / 4), dim3(256), 0, stream>>>(x, diag);
        fcm_fallback<<<dim3(256), dim3(256), 0, stream>>>(x, diag, out);
    }
}

// Round 8
// 165.011 us; speedup vs baseline: 1.6761x; 1.6761x over previous
//
#include <hip/hip_runtime.h>
#include <cfloat>

#define NB 4
#define NN 4096
#define NC 256

typedef _Float16 f16;
typedef _Float16 f16x8 __attribute__((ext_vector_type(8)));
typedef float f32x4 __attribute__((ext_vector_type(4)));

__device__ __forceinline__ void gl_lds16(const void* g, void* l) {
    __builtin_amdgcn_global_load_lds(
        (const __attribute__((address_space(1))) unsigned int*)g,
        (__attribute__((address_space(3))) unsigned int*)l, 16, 0, 0);
}

// ---------------- prep: fp32 -> f16 hi/lo split + diag ----------------
__global__ __launch_bounds__(256) void prep_kernel(const float* __restrict__ x,
                                                   f16* __restrict__ xh,
                                                   f16* __restrict__ xl,
                                                   float* __restrict__ diag) {
    const int lane = threadIdx.x & 63;
    const int wave = threadIdx.x >> 6;
    const int row  = (blockIdx.x << 2) + wave;            // 0..16383
    const float4 v = ((const float4*)(x + (size_t)row * NC))[lane];
    union { f16 h[4]; uint2 u; } H, L;
    float vv[4] = {v.x, v.y, v.z, v.w};
    float s = 0.f;
    #pragma unroll
    for (int k = 0; k < 4; ++k) {
        H.h[k] = (f16)vv[k];
        L.h[k] = (f16)(vv[k] - (float)H.h[k]);
        s = fmaf(vv[k], vv[k], s);
    }
    *(uint2*)(xh + (size_t)row * NC + lane * 4) = H.u;
    *(uint2*)(xl + (size_t)row * NC + lane * 4) = L.u;
    #pragma unroll
    for (int off = 32; off; off >>= 1) s += __shfl_xor(s, off, 64);
    if (lane == 0) diag[row] = s;
}

// ---------------- main MFMA kernel ----------------
// Fat-wave pipeline: 256 threads (4 waves), __launch_bounds__(256,1) ->
// 1 wave/SIMD -> up to 512 VGPR/wave. Stripe double-buffer + depth-2 DMA,
// counted vmcnt(8) (in-order; exactly our 8 in-loop DMAs/chunk -> exact by
// construction). LDS-side guard is ORDER-INDEPENDENT: lgkmcnt(0) at top of
// chunk; all frag reads for chunk KC+1 issue >= 1 MFMA-quarter before that
// drain, so it is ~free. A-slot 3 ping-pongs (loaded in Q2 before QUARTER(3)
// consumes the old value).
// r6/r7 FAILURE ROOT CAUSE (fixed here): diag staging passed a LANE-UNIFORM
// global address to global_load_lds; the global source must be PER-LANE
// (LDS side gets lane*16B automatically). db + seg + lane*4 is the fix.
#define TI 64
#define TJ 256
#define KCB 32
#define NCHUNK (NC / KCB)    // 8 k-chunks per j-tile
#define NJT (NN / TJ)        // 16 j-tiles

#define TRIPLE(RT, CT, AH, AL, BH, BL) \
    acc[RT][CT] = __builtin_amdgcn_mfma_f32_16x16x32_f16(AH, BH[CT], acc[RT][CT], 0, 0, 0); \
    acc[RT][CT] = __builtin_amdgcn_mfma_f32_16x16x32_f16(AH, BL[CT], acc[RT][CT], 0, 0, 0); \
    acc[RT][CT] = __builtin_amdgcn_mfma_f32_16x16x32_f16(AL, BH[CT], acc[RT][CT], 0, 0, 0);

#define QUARTER(RT, AH, AL, BH, BL) \
    TRIPLE(RT, 0, AH, AL, BH, BL) TRIPLE(RT, 1, AH, AL, BH, BL) \
    TRIPLE(RT, 2, AH, AL, BH, BL) TRIPLE(RT, 3, AH, AL, BH, BL)

// A-frag read for k-chunk KN, row-block RT, into named regs (Ah layout:
// slot g holds granule g ^ (row&7))
#define RDA(DH, DL, RT, KN) \
    DH = *(const f16x8*)&Ah[((RT) * 16 + l15) * NC + ((((KN) * 4 + quad) ^ sw) * 8)]; \
    DL = *(const f16x8*)&Al[((RT) * 16 + l15) * NC + ((((KN) * 4 + quad) ^ sw) * 8)];

#define SB __builtin_amdgcn_sched_barrier(0)

// One k-chunk (KC literal 0..7). All frags for chunk KC were loaded during
// chunk KC-1. Top: lgkmcnt(0) (order-independent, ~free), then DMA chunk
// KC+2 into the buffer chunk KC was read from. Q2: vmcnt(8) = chunk KC+1's
// DMAs retired (KC+2's 8 may fly), read all chunk-KC+1 frags.
#define CHUNK(KC, BHC, BLC, BHN, BLN, A3HC, A3LC, A3HN, A3LN) do { \
    asm volatile("s_waitcnt lgkmcnt(0)" ::: "memory"); \
    SB; \
    { \
        int jn = jt + (((KC) + 2) >> 3); if (jn >= NJT) jn = 0;   /* wrap: dummy stage */ \
        const int kn = ((KC) + 2) & 7; \
        f16* const dh = &Sh[(KC) & 1][w * 2048]; \
        f16* const dl = &Sl[(KC) & 1][w * 2048]; \
        _Pragma("unroll") \
        for (int t = 0; t < 4; ++t) { \
            const int col = jn * TJ + w * 64 + t * 16 + bcol; \
            const size_t goff = (size_t)col * NC + (size_t)(kn * KCB) + bslot * 8; \
            gl_lds16(xhb + goff, dh + t * 512); \
            gl_lds16(xlb + goff, dl + t * 512); \
        } \
    } \
    SB; \
    QUARTER(0, a0h, a0l, BHC, BLC) \
    RDA(a0h, a0l, 0, ((KC) + 1) & 7) \
    SB; \
    QUARTER(1, a1h, a1l, BHC, BLC) \
    RDA(a1h, a1l, 1, ((KC) + 1) & 7) \
    SB; \
    QUARTER(2, a2h, a2l, BHC, BLC) \
    asm volatile("s_waitcnt vmcnt(8)" ::: "memory"); \
    SB; \
    { \
        const f16* const rh = &Sh[((KC) + 1) & 1][w * 2048]; \
        const f16* const rl = &Sl[((KC) + 1) & 1][w * 2048]; \
        _Pragma("unroll") \
        for (int ct = 0; ct < 4; ++ct) { \
            const int c = ct * 16 + l15; \
            BHN[ct] = *(const f16x8*)&rh[c * KCB + gB]; \
            BLN[ct] = *(const f16x8*)&rl[c * KCB + gB]; \
        } \
    } \
    RDA(a2h, a2l, 2, ((KC) + 1) & 7) \
    RDA(A3HN, A3LN, 3, ((KC) + 1) & 7) \
    SB; \
    QUARTER(3, A3HC, A3LC, BHC, BLC) \
} while (0)

__global__ __launch_bounds__(256, 1) void fcm_mfma(const f16* __restrict__ xh,
                                                   const f16* __restrict__ xl,
                                                   const float* __restrict__ diag,
                                                   float* __restrict__ out) {
    __shared__ f16 Ah[TI * NC];          // 32 KB  persistent A hi (swizzled)
    __shared__ f16 Al[TI * NC];          // 32 KB  persistent A lo
    __shared__ f16 Sh[2][4 * 2048];      // 32 KB  B hi stripes, double-buffered
    __shared__ f16 Sl[2][4 * 2048];      // 32 KB  B lo stripes, double-buffered
    __shared__ float Dall[NN];           // 16 KB  full batch diag
    __shared__ float Scr[TI * 4 * 3];    // 3 KB   cross-wave merge

    const int tid   = threadIdx.x;
    const int bx    = blockIdx.x;
    const int batch = (bx & 7) >> 1;                  // batch -> XCD pair
    const int band  = ((bx >> 3) << 1) | (bx & 1);    // 0..63
    const int i0    = band * TI;

    const f16* __restrict__ xhb = xh + (size_t)batch * NN * NC;
    const f16* __restrict__ xlb = xl + (size_t)batch * NN * NC;
    const float* __restrict__ db = diag + (size_t)batch * NN;

    const int w    = tid >> 6;    // 0..3
    const int lane = tid & 63;
    const int quad = lane >> 4;
    const int l15  = lane & 15;
    const int sw   = l15 & 7;     // A fragment swizzle key

    // ---- A stage (once): LDS[row][granule ^ (row&7)] = x[i0+row][granule] ----
    {
        const int rsub = lane >> 5;        // 0/1
        const int s    = lane & 31;
        #pragma unroll
        for (int it = 0; it < 8; ++it) {
            const int t  = w * 8 + it;     // 0..31, 2 rows each
            const int rg = t * 2 + rsub;
            const int g  = s ^ (rg & 7);
            const size_t goff = (size_t)(i0 + rg) * NC + g * 8;
            gl_lds16(xhb + goff, Ah + t * 512);
            gl_lds16(xlb + goff, Al + t * 512);
        }
    }
    // ---- diag stage (once): 16 KB -> LDS. PER-LANE global source:
    // lane l loads db[seg+4l..+3] -> lands at Dall[seg+4l] (lane*16B auto) ----
    #pragma unroll
    for (int t = 0; t < 4; ++t) {
        const int seg = (w * 4 + t) * 256;         // 256 floats per wave-instr
        gl_lds16(db + seg + lane * 4, Dall + seg);
    }

    // B staging lane constants (16 cols x 4 granules per 1KB wave-instr)
    const int bcol  = lane >> 2;                       // col within 16-col group
    const int bslot = (lane & 3) ^ ((lane >> 3) & 3);  // source granule for this slot
    const int gB    = (quad ^ ((l15 >> 1) & 3)) * 8;   // B frag read granule (const)

    // ---- prologue: stage chunk 0 -> buf0, chunk 1 -> buf1 ----
    #pragma unroll
    for (int t = 0; t < 4; ++t) {
        const int col = w * 64 + t * 16 + bcol;
        gl_lds16(xhb + (size_t)col * NC + bslot * 8, &Sh[0][w * 2048] + t * 512);
        gl_lds16(xlb + (size_t)col * NC + bslot * 8, &Sl[0][w * 2048] + t * 512);
    }
    #pragma unroll
    for (int t = 0; t < 4; ++t) {
        const int col = w * 64 + t * 16 + bcol;
        gl_lds16(xhb + (size_t)col * NC + KCB + bslot * 8, &Sh[1][w * 2048] + t * 512);
        gl_lds16(xlb + (size_t)col * NC + KCB + bslot * 8, &Sl[1][w * 2048] + t * 512);
    }
    __syncthreads();      // drains A + diag + chunk0/1; only barrier before epilogue

    // frag registers: a0..a2 rotate in place; a3 ping-pongs (A/B);
    // bf ping-pongs (chunk KC in b{A,B} by parity)
    f16x8 a0h, a0l, a1h, a1l, a2h, a2l, a3hA, a3lA, a3hB, a3lB;
    f16x8 bAh[4], bAl[4], bBh[4], bBl[4];

    // preload chunk-0 frags, then drain lgkm once
    #pragma unroll
    for (int ct = 0; ct < 4; ++ct) {
        const int c = ct * 16 + l15;
        bAh[ct] = *(const f16x8*)&Sh[0][w * 2048 + c * KCB + gB];
        bAl[ct] = *(const f16x8*)&Sl[0][w * 2048 + c * KCB + gB];
    }
    RDA(a0h, a0l, 0, 0) RDA(a1h, a1l, 1, 0) RDA(a2h, a2l, 2, 0) RDA(a3hA, a3lA, 3, 0)
    asm volatile("s_waitcnt lgkmcnt(0)" ::: "memory");
    SB;

    // running top-2 (+argmin) for the lane's 16 row-slots (rt*4 + p)
    float m1[16], m2[16]; int i1[16];
    #pragma unroll
    for (int r = 0; r < 16; ++r) { m1[r] = FLT_MAX; m2[r] = FLT_MAX; i1[r] = 0x7fffffff; }

    for (int jt = 0; jt < NJT; ++jt) {
        f32x4 acc[4][4];
        #pragma unroll
        for (int rt = 0; rt < 4; ++rt)
            #pragma unroll
            for (int ct = 0; ct < 4; ++ct)
                acc[rt][ct] = (f32x4){0.f, 0.f, 0.f, 0.f};

        CHUNK(0, bAh, bAl, bBh, bBl, a3hA, a3lA, a3hB, a3lB);
        CHUNK(1, bBh, bBl, bAh, bAl, a3hB, a3lB, a3hA, a3lA);
        CHUNK(2, bAh, bAl, bBh, bBl, a3hA, a3lA, a3hB, a3lB);
        CHUNK(3, bBh, bBl, bAh, bAl, a3hB, a3lB, a3hA, a3lA);
        CHUNK(4, bAh, bAl, bBh, bBl, a3hA, a3lA, a3hB, a3lB);
        CHUNK(5, bBh, bBl, bAh, bAl, a3hB, a3lB, a3hA, a3lA);
        CHUNK(6, bAh, bAl, bBh, bBl, a3hA, a3lA, a3hB, a3lB);
        CHUNK(7, bBh, bBl, bAh, bAl, a3hB, a3lB, a3hA, a3lA);

        // fold j-tile into running top-2; key = diag_j - 2*dot (monotone in dist)
        #pragma unroll
        for (int ct = 0; ct < 4; ++ct) {
            const int col = jt * TJ + w * 64 + ct * 16 + l15;
            const float dj = Dall[col];                // LDS broadcast read
            #pragma unroll
            for (int rt = 0; rt < 4; ++rt) {
                #pragma unroll
                for (int p = 0; p < 4; ++p) {
                    const int rglob = i0 + rt * 16 + quad * 4 + p;
                    float v = fmaf(-2.0f, acc[rt][ct][p], dj);
                    v = (col == rglob) ? FLT_MAX : v;       // mask self
                    const int slot = rt * 4 + p;
                    const bool lt = v < m1[slot];           // strict: keep earliest j
                    m2[slot] = fminf(m2[slot], fmaxf(m1[slot], v));
                    m1[slot] = fminf(m1[slot], v);
                    i1[slot] = lt ? col : i1[slot];
                }
            }
        }
    }

    // butterfly merge across the 16 col-lanes (l15) holding the same rows
    #pragma unroll
    for (int s = 0; s < 16; ++s) {
        float a1 = m1[s], a2 = m2[s]; int ai = i1[s];
        #pragma unroll
        for (int msk = 1; msk < 16; msk <<= 1) {
            const float o1 = __shfl_xor(a1, msk, 64);
            const float o2 = __shfl_xor(a2, msk, 64);
            const int   oi = __shfl_xor(ai, msk, 64);
            const bool take = (o1 < a1) || (o1 == a1 && oi < ai);
            const float keep = take ? a1 : o1;
            a2 = fminf(fminf(a2, o2), keep);
            a1 = take ? o1 : a1;
            ai = take ? oi : ai;
        }
        m1[s] = a1; m2[s] = a2; i1[s] = ai;
    }
    if (l15 == 0) {
        #pragma unroll
        for (int s = 0; s < 16; ++s) {
            const int rloc = (s >> 2) * 16 + quad * 4 + (s & 3);
            float* p = &Scr[(rloc * 4 + w) * 3];
            p[0] = m1[s]; p[1] = __int_as_float(i1[s]); p[2] = m2[s];
        }
    }
    __syncthreads();
    if (tid < TI) {
        float M1 = FLT_MAX, M2 = FLT_MAX; int I1 = 0x7fffffff;
        #pragma unroll
        for (int t = 0; t < 4; ++t) {
            const float* p = &Scr[(tid * 4 + t) * 3];
            const float o1 = p[0]; const int oi = __float_as_int(p[1]); const float o2 = p[2];
            const bool take = (o1 < M1) || (o1 == M1 && oi < I1);
            const float keep = take ? M1 : o1;
            M2 = fminf(fminf(M2, o2), keep);
            M1 = take ? o1 : M1;
            I1 = take ? oi : I1;
        }
        const int   gi = i0 + tid;
        const float di = Dall[gi];
        const float d1 = sqrtf(fmaxf(di + M1, 0.0f) + 1e-9f);
        const float d2 = sqrtf(fmaxf(di + M2, 0.0f) + 1e-9f);
        const float e  = expf(d1);
        const float pred = (d1 / d2 < 0.6f) ? 2.0f / (1.0f + e)
                                            : 2.0f / (1.0f + 2.0f * e);
        out[(size_t)batch * NN + gi] = pred;
        out[(size_t)NB * NN + (size_t)batch * NN + gi] = (float)I1;
    }
}

// ---------------- fp32 fallback (round-1, passed) if ws too small ----------------
__global__ __launch_bounds__(256) void diag_kernel(const float* __restrict__ x,
                                                   float* __restrict__ diag) {
    const int lane = threadIdx.x & 63;
    const int wave = threadIdx.x >> 6;
    const int row  = (blockIdx.x << 2) + wave;
    const float4 v = ((const float4*)(x + (size_t)row * NC))[lane];
    float s = v.x * v.x + v.y * v.y + v.z * v.z + v.w * v.w;
    #pragma unroll
    for (int off = 32; off; off >>= 1) s += __shfl_xor(s, off, 64);
    if (lane == 0) diag[row] = s;
}

#define FTI 64
#define FTJ 256
#define FKC 16

__global__ __launch_bounds__(256) void fcm_fallback(const float* __restrict__ x,
                                                    const float* __restrict__ diag,
                                                    float* __restrict__ out) {
    __shared__ float As[FKC * FTI];
    __shared__ float Bs[FKC * FTJ];
    __shared__ float Dsf[FTJ];
    __shared__ float Scrf[FTI * 32 * 3];

    const int tid = threadIdx.x;
    const int bx  = blockIdx.x;
    const int batch = (bx & 7) >> 1;
    const int tile  = ((bx >> 3) << 1) | (bx & 1);
    const int i0    = tile * FTI;
    const float* __restrict__ xb = x + (size_t)batch * NN * NC;
    const float* __restrict__ db = diag + (size_t)batch * NN;
    const int tx = tid & 31;
    const int ty = tid >> 5;
    const int sr  = tid & 63;
    const int sk0 = (tid >> 6) << 2;

    float m1[8], m2[8]; int i1[8];
    #pragma unroll
    for (int r = 0; r < 8; ++r) { m1[r] = FLT_MAX; m2[r] = FLT_MAX; i1[r] = 0; }

    for (int jt = 0; jt < NN / FTJ; ++jt) {
        const int j0 = jt * FTJ;
        __syncthreads();
        Dsf[tid] = db[j0 + tid];
        float acc[8][8];
        #pragma unroll
        for (int r = 0; r < 8; ++r)
            #pragma unroll
            for (int c = 0; c < 8; ++c) acc[r][c] = 0.0f;
        float4 pa  = *(const float4*)(xb + (size_t)(i0 + sr) * NC + sk0);
        const float* bsrc = xb + (size_t)(j0 + tid) * NC;
        float4 pb0 = *(const float4*)(bsrc + 0);
        float4 pb1 = *(const float4*)(bsrc + 4);
        float4 pb2 = *(const float4*)(bsrc + 8);
        float4 pb3 = *(const float4*)(bsrc + 12);
        for (int kc = 0; kc < NC / FKC; ++kc) {
            __syncthreads();
            As[(sk0 + 0) * FTI + sr] = pa.x;
            As[(sk0 + 1) * FTI + sr] = pa.y;
            As[(sk0 + 2) * FTI + sr] = pa.z;
            As[(sk0 + 3) * FTI + sr] = pa.w;
            Bs[ 0 * FTJ + tid] = pb0.x; Bs[ 1 * FTJ + tid] = pb0.y;
            Bs[ 2 * FTJ + tid] = pb0.z; Bs[ 3 * FTJ + tid] = pb0.w;
            Bs[ 4 * FTJ + tid] = pb1.x; Bs[ 5 * FTJ + tid] = pb1.y;
            Bs[ 6 * FTJ + tid] = pb1.z; Bs[ 7 * FTJ + tid] = pb1.w;
            Bs[ 8 * FTJ + tid] = pb2.x; Bs[ 9 * FTJ + tid] = pb2.y;
            Bs[10 * FTJ + tid] = pb2.z; Bs[11 * FTJ + tid] = pb2.w;
            Bs[12 * FTJ + tid] = pb3.x; Bs[13 * FTJ + tid] = pb3.y;
            Bs[14 * FTJ + tid] = pb3.z; Bs[15 * FTJ + tid] = pb3.w;
            if (kc + 1 < NC / FKC) {
                const int kb = (kc + 1) * FKC;
                pa  = *(const float4*)(xb + (size_t)(i0 + sr) * NC + kb + sk0);
                pb0 = *(const float4*)(bsrc + kb + 0);
                pb1 = *(const float4*)(bsrc + kb + 4);
                pb2 = *(const float4*)(bsrc + kb + 8);
                pb3 = *(const float4*)(bsrc + kb + 12);
            }
            __syncthreads();
            #pragma unroll
            for (int k = 0; k < FKC; ++k) {
                float av[8], bv[8];
                *(float4*)&av[0] = *(const float4*)&As[k * FTI + ty * 8];
                *(float4*)&av[4] = *(const float4*)&As[k * FTI + ty * 8 + 4];
                *(float4*)&bv[0] = *(const float4*)&Bs[k * FTJ + tx * 8];
                *(float4*)&bv[4] = *(const float4*)&Bs[k * FTJ + tx * 8 + 4];
                #pragma unroll
                for (int r = 0; r < 8; ++r)
                    #pragma unroll
                    for (int c = 0; c < 8; ++c)
                        acc[r][c] = fmaf(av[r], bv[c], acc[r][c]);
            }
        }
        #pragma unroll
        for (int c = 0; c < 8; ++c) {
            const int j = j0 + tx * 8 + c;
            const float dj = Dsf[tx * 8 + c];
            #pragma unroll
            for (int r = 0; r < 8; ++r) {
                const int ig = i0 + ty * 8 + r;
                float v = fmaf(-2.0f, acc[r][c], dj);
                v = (j == ig) ? FLT_MAX : v;
                const bool lt = v < m1[r];
                m2[r] = fminf(m2[r], fmaxf(m1[r], v));
                m1[r] = fminf(m1[r], v);
                i1[r] = lt ? j : i1[r];
            }
        }
    }
    __syncthreads();
    #pragma unroll
    for (int r = 0; r < 8; ++r) {
        float* s = &Scrf[((ty * 8 + r) * 32 + tx) * 3];
        s[0] = m1[r]; s[1] = __int_as_float(i1[r]); s[2] = m2[r];
    }
    __syncthreads();
    if (tid < FTI) {
        float M1 = FLT_MAX, M2 = FLT_MAX; int I1 = 0;
        for (int t = 0; t < 32; ++t) {
            const float* s = &Scrf[(tid * 32 + t) * 3];
            const float v1 = s[0]; const int ii = __float_as_int(s[1]);
            const float v2 = s[2];
            if (v1 < M1 || (v1 == M1 && ii < I1)) {
                M2 = fminf(M2, M1); M1 = v1; I1 = ii;
            } else {
                M2 = fminf(M2, v1);
            }
            M2 = fminf(M2, v2);
        }
        const int   gi = i0 + tid;
        const float di = db[gi];
        const float d1 = sqrtf(fmaxf(di + M1, 0.0f) + 1e-9f);
        const float d2 = sqrtf(fmaxf(di + M2, 0.0f) + 1e-9f);
        const float e  = expf(d1);
        const float pred = (d1 / d2 < 0.6f) ? 2.0f / (1.0f + e)
                                            : 2.0f / (1.0f + 2.0f * e);
        out[(size_t)batch * NN + gi] = pred;
        out[(size_t)NB * NN + (size_t)batch * NN + gi] = (float)I1;
    }
}

extern "C" void kernel_launch(void* const* d_in, const int* in_sizes, int n_in,
                              void* d_out, int out_size, void* d_ws, size_t ws_size,
                              hipStream_t stream) {
    const float* x = (const float*)d_in[0];
    float* out     = (float*)d_out;
    const size_t n_elem = (size_t)NB * NN * NC;
    const size_t need   = n_elem * 2 * 2 + (size_t)NB * NN * 4;   // hi+lo f16 + diag
    if (ws_size >= need) {
        f16*   xh   = (f16*)d_ws;
        f16*   xl   = xh + n_elem;
        float* diag = (float*)(xl + n_elem);
        prep_kernel<<<dim3(NB * NN / 4), dim3(256), 0, stream>>>(x, xh, xl, diag);
        fcm_mfma<<<dim3(256), dim3(256), 0, stream>>>(xh, xl, diag, out);
    } else {
        float* diag = (float*)d_ws;
        diag_kernel<<<dim3(NB * NN / 4), dim3(256), 0, stream>>>(x, diag);
        fcm_fallback<<<dim3(256), dim3(256), 0, stream>>>(x, diag, out);
    }
}